// Round 10
// baseline (168.832 us; speedup 1.0000x reference)
//
#include <hip/hip_runtime.h>
#include <math.h>

#define B_ 2
#define L_ 1024
#define D_ 512
#define NROW 2048
#define RS 288                  // R stride: key16|query16|g1 256
#define PI_F 3.14159274f
#define TWO_PI_F 6.28318548f

typedef __attribute__((ext_vector_type(8))) short bf16x8;
typedef __attribute__((ext_vector_type(4))) float f32x4;

__device__ __forceinline__ unsigned short f2bf(float f) {
    unsigned u = __float_as_uint(f);
    unsigned r = (u + 0x7FFFu + ((u >> 16) & 1u)) >> 16;
    return (unsigned short)r;
}
__device__ __forceinline__ float bf2f(unsigned short h) {
    return __uint_as_float((unsigned)h << 16);
}
__device__ __forceinline__ unsigned pack2(float a, float b) {
    return (unsigned)f2bf(a) | ((unsigned)f2bf(b) << 16);
}

// ---------------- weight prep + x cast + gtab (verified R9) ----------------
__global__ __launch_bounds__(256) void k_prep_w(
    const float* __restrict__ keyw, const float* __restrict__ qryw,
    const float* __restrict__ g1w, const float* __restrict__ vw,
    const float* __restrict__ outw, const float* __restrict__ x,
    const float* __restrict__ pf,
    unsigned short* __restrict__ W, unsigned short* __restrict__ xb,
    float* __restrict__ gtab)
{
    const int bx = blockIdx.x;
    const int tid = threadIdx.x;
    if (bx >= 304) {                       // gtab
        #pragma unroll
        for (int j = 0; j < 4; ++j) {
            const int l = tid * 4 + j;
            float g = 0.f;
            #pragma unroll
            for (int p = 0; p < 16; ++p)
                g += cosf(TWO_PI_F * (float)l * pf[p]);
            gtab[l] = g;
        }
        return;
    }
    if (bx >= 176) {                       // x cast
        const int chunk = (bx - 176) * 2048;
        const float4* x4 = (const float4*)x;
        ushort4* xb4 = (ushort4*)xb;
        #pragma unroll
        for (int j = 0; j < 8; ++j) {
            float4 v = x4[chunk + j * 256 + tid];
            ushort4 o;
            o.x = f2bf(v.x); o.y = f2bf(v.y); o.z = f2bf(v.z); o.w = f2bf(v.w);
            xb4[chunk + j * 256 + tid] = o;
        }
        return;
    }
    const int nt = bx % 22;
    const int kt = bx / 22;
    const int n0 = nt * 64, k0 = kt * 64;
    __shared__ unsigned short tile[64 * 68];
    const int tn = tid & 63;
    const int tk4 = tid >> 6;
    const int n = n0 + tn;
    const float* src = nullptr; int stride = 0, col = 0;
    if (n < 16)        { src = keyw; stride = 16;  col = n; }
    else if (n < 32)   { src = qryw; stride = 16;  col = n - 16; }
    else if (n < 288)  { src = g1w;  stride = 256; col = n - 32; }
    else if (n < 800)  { src = vw;   stride = 512; col = n - 288; }
    else if (n < 896)  { src = nullptr; }
    else               { src = outw; stride = 512; col = n - 896; }
    #pragma unroll
    for (int r = 0; r < 16; ++r) {
        int k = k0 + tk4 * 16 + r;
        float v = src ? src[(size_t)k * stride + col] : 0.f;
        tile[(tk4 * 16 + r) * 68 + tn] = f2bf(v);
    }
    __syncthreads();
    #pragma unroll
    for (int r = 0; r < 16; ++r) {
        int nn = n0 + tk4 * 16 + r;
        W[(size_t)nn * 512 + k0 + tn] = tile[tn * 68 + tk4 * 16 + r];
    }
}

// ---------------- GEMM1: 1D grid 448, XCD-swizzled by m-tile; V epilogue LDS-bounced ----------------
__global__ __launch_bounds__(256) void k_gemm1v(
    const unsigned short* __restrict__ xb,
    const unsigned short* __restrict__ Bt,
    const float* __restrict__ g1b, const float* __restrict__ vb,
    float* __restrict__ R,
    unsigned short* __restrict__ Vthi, unsigned short* __restrict__ Vtlo)
{
    __shared__ unsigned short As[64 * 32];
    __shared__ unsigned short Bs[64 * 32];
    __shared__ unsigned short tileV[64 * 68];
    const int bid = blockIdx.x;            // 448
    const int xcd = bid & 7;
    const int s = bid >> 3;                // 0..55
    const int nx = s % 14;
    const int myh = s / 14;                // 0..3
    const int m0 = (xcd + 8 * myh) * 64;   // same-m0 blocks share an XCD -> xb L2-hits
    const int n0 = nx * 64;
    const int tid = threadIdx.x;
    const int w = tid >> 6;
    const int lane = tid & 63;
    const int srow = tid >> 2;
    const int scol = (tid & 3) * 8;
    const int quad = lane >> 4, r16 = lane & 15;

    f32x4 acc[4];
    #pragma unroll
    for (int mt = 0; mt < 4; ++mt) acc[mt] = (f32x4){0.f, 0.f, 0.f, 0.f};

    const unsigned short* ap = xb + (size_t)(m0 + srow) * 512 + scol;
    const unsigned short* bp = Bt + (size_t)(n0 + srow) * 512 + scol;

    for (int k0 = 0; k0 < 512; k0 += 32) {
        int4 av = *(const int4*)(ap + k0);
        int4 bv = *(const int4*)(bp + k0);
        __syncthreads();
        *(int4*)&As[srow * 32 + scol] = av;
        *(int4*)&Bs[srow * 32 + scol] = bv;
        __syncthreads();
        bf16x8 bfr = *(const bf16x8*)&Bs[(w * 16 + r16) * 32 + quad * 8];
        #pragma unroll
        for (int mt = 0; mt < 4; ++mt) {
            bf16x8 af = *(const bf16x8*)&As[(mt * 16 + r16) * 32 + quad * 8];
            acc[mt] = __builtin_amdgcn_mfma_f32_16x16x32_bf16(af, bfr, acc[mt], 0, 0, 0);
        }
    }

    const int n = n0 + w * 16 + r16;
    if (n < 288) {
        const float bias = (n >= 32) ? g1b[n - 32] : 0.f;
        #pragma unroll
        for (int mt = 0; mt < 4; ++mt)
            #pragma unroll
            for (int i = 0; i < 4; ++i) {
                const int m = m0 + mt * 16 + quad * 4 + i;
                R[(size_t)m * RS + n] = acc[mt][i] + bias;
            }
    }
    if (n0 + 64 > 288 && n0 < 800) {       // tile overlaps V range: bounce through LDS
        const bool vok = (n >= 288 && n < 800);
        const float bias = vok ? vb[n - 288] : 0.f;
        #pragma unroll
        for (int pass = 0; pass < 2; ++pass) {
            __syncthreads();
            if (vok) {
                #pragma unroll
                for (int mt = 0; mt < 4; ++mt)
                    #pragma unroll
                    for (int i = 0; i < 4; ++i) {
                        float v = acc[mt][i] + bias;
                        unsigned short hi = f2bf(v);
                        tileV[(w * 16 + r16) * 68 + mt * 16 + quad * 4 + i] =
                            pass == 0 ? hi : f2bf(v - bf2f(hi));
                    }
            }
            __syncthreads();
            const int dloc = tid >> 2, part = tid & 3;
            const int d = n0 - 288 + dloc;
            if (d >= 0 && d < 512) {
                unsigned short* dst = (pass == 0 ? Vthi : Vtlo)
                                    + (size_t)d * 2048 + m0 + part * 16;
                *(int4*)dst       = *(const int4*)&tileV[dloc * 68 + part * 16];
                *(int4*)(dst + 8) = *(const int4*)&tileV[dloc * 68 + part * 16 + 8];
            }
        }
    }
}

// ---------------- phasors, jk/jq, gate + compact jkT (verified R7/R9) ----------------
__global__ __launch_bounds__(256) void k_phasor(
    const float* __restrict__ R,
    const float* __restrict__ g2w, const float* __restrict__ g2b,
    float* __restrict__ scal, float* __restrict__ jkT)
{
    const int row = blockIdx.x * 4 + (threadIdx.x >> 6);
    const int lane = threadIdx.x & 63;
    const int b = row >> 10, l = row & (L_ - 1);
    float* sc = scal + (size_t)row * 128;
    const float* r = R + (size_t)row * RS;

    float part = 0.f;
    #pragma unroll
    for (int j = 0; j < 4; ++j) {
        float v = r[32 + lane * 4 + j];
        float h = 0.5f * v * (1.0f + erff(v * 0.70710678f));
        part += h * g2w[lane * 4 + j];
    }
    #pragma unroll
    for (int off = 32; off > 0; off >>= 1) part += __shfl_down(part, off, 64);
    if (lane == 0) sc[112] = 1.0f / (1.0f + expf(-(part + g2b[0])));

    float pr = 1.f, pim = 0.f;
    if (lane < 32) {
        float a = tanhf(r[lane]) * PI_F;
        float sv, cv;
        sincosf(a, &sv, &cv);
        int t = lane & 15;
        if (lane < 16) { sc[t] = cv; sc[16 + t] = sv; }
        else           { sc[32 + t] = cv; sc[48 + t] = sv; }
        pr = cv; pim = sv;
    }
    #pragma unroll
    for (int m = 4; m <= 8; m <<= 1) {
        float orr = __shfl_xor(pr, m, 64);
        float oii = __shfl_xor(pim, m, 64);
        float nr = pr * orr - pim * oii;
        float ni = pr * oii + pim * orr;
        pr = nr; pim = ni;
    }
    if (lane < 4) {
        sc[64 + lane] = pr; sc[68 + lane] = pim;
        jkT[(size_t)(b * 8 + lane) * L_ + l]     = pr;
        jkT[(size_t)(b * 8 + 4 + lane) * L_ + l] = pim;
    } else if (lane >= 16 && lane < 20) {
        sc[72 + lane - 16] = pr; sc[76 + lane - 16] = pim;
    }
}

// ---------------- wide block scan: 16 channels (verified R8/R9) ----------------
__global__ __launch_bounds__(256) void k_scan16(
    const float* __restrict__ jkT, float* __restrict__ kmT)
{
    const int bx = blockIdx.x;
    const int tid = threadIdx.x;
    const int lane = tid & 63, wv = tid >> 6;
    __shared__ float wtot[4];
    float4 v = ((const float4*)(jkT + (size_t)bx * L_))[tid];
    float s = v.x + v.y + v.z + v.w;
    float incl = s;
    #pragma unroll
    for (int off = 1; off < 64; off <<= 1) {
        float o = __shfl_up(incl, off, 64);
        if (lane >= off) incl += o;
    }
    if (lane == 63) wtot[wv] = incl;
    __syncthreads();
    float pre = incl - s;
    for (int w2 = 0; w2 < wv; ++w2) pre += wtot[w2];
    float4 out;
    out.x = pre;
    out.y = pre + v.x;
    out.z = out.y + v.y;
    out.w = out.z + v.z;
    ((float4*)(kmT + (size_t)bx * L_))[tid] = out;
}

// ---------------- build: wgv inline + Qf/Kf rows (verified R8/R9) ----------------
__global__ __launch_bounds__(256) void k_build(
    const float* __restrict__ scal, const float* __restrict__ kmT,
    const float* __restrict__ res_scale, const float* __restrict__ res_thr,
    const float* __restrict__ sur_scale, const float* __restrict__ sur_bias,
    const float* __restrict__ setw,
    unsigned short* __restrict__ Qf, unsigned short* __restrict__ Kf)
{
    const int rowi = blockIdx.x * 8 + (threadIdx.x >> 5);
    const int sub = threadIdx.x & 31;
    const int b = rowi >> 10, l = rowi & (L_ - 1);
    const float* sc = scal + (size_t)rowi * 128;

    float mag = 0.f;
    #pragma unroll
    for (int pp = 0; pp < 4; ++pp) {
        float kmr = kmT[(size_t)(b * 8 + pp) * L_ + l];
        float kmi = kmT[(size_t)(b * 8 + 4 + pp) * L_ + l];
        float jqr = sc[72 + pp], jqi = sc[76 + pp];
        float re = kmr * jqr + kmi * jqi;
        float im = kmi * jqr - kmr * jqi;
        mag += sqrtf(re * re + im * im);
    }
    mag *= 0.25f;
    float posn = fmaxf((float)l, 1.0f);
    float nres = mag / sqrtf(posn);
    float scl = fminf(fmaxf(res_scale[0], 1.0f), 20.0f);
    float thr = fminf(fmaxf(res_thr[0], 0.1f), 0.9f);
    float sur = 0.5f * (1.0f - tanhf(scl * (nres - thr)));
    float wgv = 1.0f / (1.0f + expf(-(sur_scale[0] * (sur - 0.5f) + sur_bias[0])));

    const float gate = sc[112];
    float s0 = setw[0], s1 = setw[1], s2 = setw[2], s3 = setw[3];
    float mx = fmaxf(fmaxf(s0, s1), fmaxf(s2, s3));
    float e0 = expf(s0 - mx), e1 = expf(s1 - mx), e2 = expf(s2 - mx), e3 = expf(s3 - mx);
    float esum = e0 + e1 + e2 + e3;
    const float qs = 0.2f * gate;

    unsigned* qp = (unsigned*)(Qf + (size_t)rowi * 64);
    unsigned* kp = (unsigned*)(Kf + (size_t)rowi * 64);
    if (sub < 16) {
        float wgrp = ((sub >> 2) == 0 ? e0 : (sub >> 2) == 1 ? e1 : (sub >> 2) == 2 ? e2 : e3) / esum;
        qp[sub] = pack2(qs * wgrp * sc[32 + sub], qs * wgrp * sc[48 + sub]);
        kp[sub] = pack2(wgv * sc[sub], wgv * sc[16 + sub]);
    } else if (sub < 20) {
        int p = sub - 16;
        qp[16 + p] = pack2(qs * sc[72 + p], qs * sc[76 + p]);
        kp[16 + p] = pack2(wgv * sc[64 + p], wgv * sc[68 + p]);
    } else {
        qp[sub] = 0u; kp[sub] = 0u;
    }
}

// ---------------- build A: MFMA (verified R3) + LDS-bounced coalesced int4 stores ----------------
__global__ __launch_bounds__(256) void k_buildA(
    const unsigned short* __restrict__ Qf, const unsigned short* __restrict__ Kf,
    const float* __restrict__ scal, const float* __restrict__ gtab,
    const float* __restrict__ posw,
    unsigned short* __restrict__ Ahi, unsigned short* __restrict__ Alo)
{
    const int bx = blockIdx.x;
    const int b = bx / 136;
    const int r = bx % 136;
    int ti = 0;
    while ((ti + 1) * (ti + 2) / 2 <= r) ++ti;
    const int tj = r - ti * (ti + 1) / 2;

    __shared__ unsigned short Qs[64 * 72];
    __shared__ unsigned short Ks[64 * 72];
    const int tid = threadIdx.x;
    const int srow = tid >> 2;
    const int sc16 = (tid & 3) * 16;
    {
        const unsigned short* qsrc = Qf + ((size_t)(b * L_ + ti * 64 + srow)) * 64 + sc16;
        const unsigned short* ksrc = Kf + ((size_t)(b * L_ + tj * 64 + srow)) * 64 + sc16;
        *(int4*)&Qs[srow * 72 + sc16]     = *(const int4*)(qsrc);
        *(int4*)&Qs[srow * 72 + sc16 + 8] = *(const int4*)(qsrc + 8);
        *(int4*)&Ks[srow * 72 + sc16]     = *(const int4*)(ksrc);
        *(int4*)&Ks[srow * 72 + sc16 + 8] = *(const int4*)(ksrc + 8);
    }
    __syncthreads();

    const int w = tid >> 6;
    const int lane = tid & 63;
    const int quad = lane >> 4, r16 = lane & 15;
    f32x4 acc[4];
    #pragma unroll
    for (int mt = 0; mt < 4; ++mt) acc[mt] = (f32x4){0.f, 0.f, 0.f, 0.f};
    #pragma unroll
    for (int kk = 0; kk < 2; ++kk) {
        bf16x8 bfr = *(const bf16x8*)&Ks[(w * 16 + r16) * 72 + kk * 32 + quad * 8];
        #pragma unroll
        for (int mt = 0; mt < 4; ++mt) {
            bf16x8 af = *(const bf16x8*)&Qs[(mt * 16 + r16) * 72 + kk * 32 + quad * 8];
            acc[mt] = __builtin_amdgcn_mfma_f32_16x16x32_bf16(af, bfr, acc[mt], 0, 0, 0);
        }
    }
    const float sw = 1.0f / (1.0f + expf(-posw[0]));
    const int lp = tj * 64 + w * 16 + r16;
    const int lc = w * 16 + r16;
    float vv[16];
    #pragma unroll
    for (int mt = 0; mt < 4; ++mt)
        #pragma unroll
        for (int i = 0; i < 4; ++i) {
            const int l = ti * 64 + mt * 16 + quad * 4 + i;
            const int dl = l - lp;
            float v = 0.f;
            if (dl >= 0) {
                float gate = scal[((size_t)(b * L_ + l)) * 128 + 112];
                v = acc[mt][i] + (1.0f - gate) * sw * gtab[dl];
            }
            vv[mt * 4 + i] = v;
        }
    unsigned short* tileA = Qs;           // reuse (9216 >= 64*68)
    #pragma unroll
    for (int pass = 0; pass < 2; ++pass) {
        __syncthreads();                   // pass0: MFMA reads of Qs done
        #pragma unroll
        for (int mt = 0; mt < 4; ++mt)
            #pragma unroll
            for (int i = 0; i < 4; ++i) {
                const int lr = mt * 16 + quad * 4 + i;
                float v = vv[mt * 4 + i];
                unsigned short hi = f2bf(v);
                tileA[lr * 68 + lc] = pass == 0 ? hi : f2bf(v - bf2f(hi));
            }
        __syncthreads();
        const int lr2 = tid >> 2, part = tid & 3;
        unsigned short* dst = (pass == 0 ? Ahi : Alo)
            + ((size_t)(b * L_ + ti * 64 + lr2)) * 1024 + tj * 64 + part * 16;
        *(int4*)dst       = *(const int4*)&tileA[lr2 * 68 + part * 16];
        *(int4*)(dst + 8) = *(const int4*)&tileA[lr2 * 68 + part * 16 + 8];
    }
}

// ---------------- AV GEMM, h-split + b-flip, XCD-swizzled by ti (A L2-locality) ----------------
__global__ __launch_bounds__(256) void k_avH(
    const unsigned short* __restrict__ Ahi, const unsigned short* __restrict__ Alo,
    const unsigned short* __restrict__ Vthi, const unsigned short* __restrict__ Vtlo,
    float* __restrict__ parts)
{
    const int bid = blockIdx.x;         // 512
    const int xcd = bid & 7;            // all 16 (nj,h) blocks of one (b,ti) share an XCD
    const int s = bid >> 3;             // 0..63
    const int h = s & 1;
    const int nj = (s >> 1) & 7;
    const int tih = (s >> 4) & 1;
    const int b = s >> 5;
    const int ti_raw = xcd + 8 * tih;
    const int ti = b ? (15 - ti_raw) : ti_raw;   // per-XCD work: (x+1)+(x+9)+(16-x)+(8-x)=34
    const int m0 = ti * 64, n0 = nj * 64;
    const int nh = (ti + 2) >> 1;
    const int kbeg = (h ? nh : 0) * 64;
    const int kend = (h ? (ti + 1) : nh) * 64;
    float* prt = parts + (size_t)h * NROW * 512;

    __shared__ unsigned short Ash[64 * 32];
    __shared__ unsigned short Asl[64 * 32];
    __shared__ unsigned short Bsh[64 * 32];
    __shared__ unsigned short Bsl[64 * 32];
    const int tid = threadIdx.x;
    const int w = tid >> 6;
    const int lane = tid & 63;
    const int srow = tid >> 2;
    const int scol = (tid & 3) * 8;
    const int quad = lane >> 4, r16 = lane & 15;

    f32x4 acc[4];
    #pragma unroll
    for (int mt = 0; mt < 4; ++mt) acc[mt] = (f32x4){0.f, 0.f, 0.f, 0.f};

    const unsigned short* aph = Ahi + ((size_t)(b * L_ + m0 + srow)) * 1024 + scol;
    const unsigned short* apl = Alo + ((size_t)(b * L_ + m0 + srow)) * 1024 + scol;
    const unsigned short* bph = Vthi + (size_t)(n0 + srow) * 2048 + b * L_ + scol;
    const unsigned short* bpl = Vtlo + (size_t)(n0 + srow) * 2048 + b * L_ + scol;

    for (int k0 = kbeg; k0 < kend; k0 += 32) {
        int4 ah = *(const int4*)(aph + k0);
        int4 al = *(const int4*)(apl + k0);
        int4 bh = *(const int4*)(bph + k0);
        int4 bl = *(const int4*)(bpl + k0);
        __syncthreads();
        *(int4*)&Ash[srow * 32 + scol] = ah;
        *(int4*)&Asl[srow * 32 + scol] = al;
        *(int4*)&Bsh[srow * 32 + scol] = bh;
        *(int4*)&Bsl[srow * 32 + scol] = bl;
        __syncthreads();
        bf16x8 bh8 = *(const bf16x8*)&Bsh[(w * 16 + r16) * 32 + quad * 8];
        bf16x8 bl8 = *(const bf16x8*)&Bsl[(w * 16 + r16) * 32 + quad * 8];
        #pragma unroll
        for (int mt = 0; mt < 4; ++mt) {
            bf16x8 ah8 = *(const bf16x8*)&Ash[(mt * 16 + r16) * 32 + quad * 8];
            bf16x8 al8 = *(const bf16x8*)&Asl[(mt * 16 + r16) * 32 + quad * 8];
            acc[mt] = __builtin_amdgcn_mfma_f32_16x16x32_bf16(ah8, bh8, acc[mt], 0, 0, 0);
            acc[mt] = __builtin_amdgcn_mfma_f32_16x16x32_bf16(ah8, bl8, acc[mt], 0, 0, 0);
            acc[mt] = __builtin_amdgcn_mfma_f32_16x16x32_bf16(al8, bh8, acc[mt], 0, 0, 0);
        }
    }
    const int n = n0 + w * 16 + r16;
    #pragma unroll
    for (int mt = 0; mt < 4; ++mt)
        #pragma unroll
        for (int i = 0; i < 4; ++i)
            prt[((size_t)(b * L_ + m0 + mt * 16 + quad * 4 + i)) * 512 + n] = acc[mt][i];
}

// ---------------- LN: y = (p0+p1)/nf, LayerNorm, bf16 out (verified R9) ----------------
__global__ __launch_bounds__(512) void k_ln2(
    const float* __restrict__ parts,
    const float* __restrict__ lng, const float* __restrict__ lnb,
    unsigned short* __restrict__ locb)
{
    const int row = blockIdx.x;
    const int l = row & (L_ - 1);
    const int d = threadIdx.x;
    __shared__ float red[16];
    float y = (parts[(size_t)row * 512 + d]
             + parts[(size_t)NROW * 512 + (size_t)row * 512 + d])
            / sqrtf(4.0f * (float)(l + 1));
    float s = y, s2v = y * y;
    #pragma unroll
    for (int off = 32; off > 0; off >>= 1) {
        s   += __shfl_down(s, off, 64);
        s2v += __shfl_down(s2v, off, 64);
    }
    const int lane = d & 63, wv = d >> 6;
    if (lane == 0) { red[wv] = s; red[8 + wv] = s2v; }
    __syncthreads();
    float su = 0.f, sq = 0.f;
    #pragma unroll
    for (int w2 = 0; w2 < 8; ++w2) { su += red[w2]; sq += red[8 + w2]; }
    float mu = su * (1.0f / 512.0f);
    float var = sq * (1.0f / 512.0f) - mu * mu;
    float rstd = rsqrtf(var + 1e-5f);
    float yn = (y - mu) * rstd * lng[d] + lnb[d];
    locb[(size_t)row * 512 + d] = f2bf(yn);
}

// ---------------- out GEMM: 1D grid 256, XCD-swizzled by m-tile (locb L2-locality) ----------------
__global__ __launch_bounds__(256) void k_gemm_out(
    const unsigned short* __restrict__ A,
    const unsigned short* __restrict__ Bt,
    const float* __restrict__ bias, const float* __restrict__ resid,
    float* __restrict__ out)
{
    __shared__ unsigned short As[64 * 32];
    __shared__ unsigned short Bs[64 * 32];
    const int bid = blockIdx.x;            // 256
    const int xcd = bid & 7;
    const int s = bid >> 3;                // 0..31
    const int nx = s & 7;
    const int myh = s >> 3;                // 0..3
    const int m0 = (xcd + 8 * myh) * 64;
    const int n0 = nx * 64;
    const int tid = threadIdx.x;
    const int w = tid >> 6;
    const int lane = tid & 63;
    const int srow = tid >> 2;
    const int scol = (tid & 3) * 8;
    const int quad = lane >> 4, r16 = lane & 15;

    f32x4 acc[4];
    #pragma unroll
    for (int mt = 0; mt < 4; ++mt) acc[mt] = (f32x4){0.f, 0.f, 0.f, 0.f};

    const unsigned short* ap = A  + (size_t)(m0 + srow) * 512 + scol;
    const unsigned short* bp = Bt + (size_t)(n0 + srow) * 512 + scol;

    for (int k0 = 0; k0 < 512; k0 += 32) {
        int4 av = *(const int4*)(ap + k0);
        int4 bv = *(const int4*)(bp + k0);
        __syncthreads();
        *(int4*)&As[srow * 32 + scol] = av;
        *(int4*)&Bs[srow * 32 + scol] = bv;
        __syncthreads();
        bf16x8 bfr = *(const bf16x8*)&Bs[(w * 16 + r16) * 32 + quad * 8];
        #pragma unroll
        for (int mt = 0; mt < 4; ++mt) {
            bf16x8 af = *(const bf16x8*)&As[(mt * 16 + r16) * 32 + quad * 8];
            acc[mt] = __builtin_amdgcn_mfma_f32_16x16x32_bf16(af, bfr, acc[mt], 0, 0, 0);
        }
    }
    const int n = n0 + w * 16 + r16;
    const float bn = bias[n];
    #pragma unroll
    for (int mt = 0; mt < 4; ++mt) {
        #pragma unroll
        for (int i = 0; i < 4; ++i) {
            const int m = m0 + mt * 16 + quad * 4 + i;
            out[(size_t)m * 512 + n] = acc[mt][i] + bn + resid[(size_t)m * 512 + n];
        }
    }
}

extern "C" void kernel_launch(void* const* d_in, const int* in_sizes, int n_in,
                              void* d_out, int out_size, void* d_ws, size_t ws_size,
                              hipStream_t stream)
{
    const float* x      = (const float*)d_in[0];
    const float* keyw   = (const float*)d_in[1];
    const float* qryw   = (const float*)d_in[2];
    const float* vw     = (const float*)d_in[4];
    const float* vb     = (const float*)d_in[5];
    const float* lng    = (const float*)d_in[6];
    const float* lnb    = (const float*)d_in[7];
    const float* outw   = (const float*)d_in[8];
    const float* outb   = (const float*)d_in[9];
    const float* setw   = (const float*)d_in[10];
    const float* pf     = (const float*)d_in[11];
    const float* posw   = (const float*)d_in[12];
    const float* g1w    = (const float*)d_in[13];
    const float* g1b    = (const float*)d_in[14];
    const float* g2w    = (const float*)d_in[15];
    const float* g2b    = (const float*)d_in[16];
    const float* sscale = (const float*)d_in[19];
    const float* sbias  = (const float*)d_in[20];
    const float* rscale = (const float*)d_in[21];
    const float* rthr   = (const float*)d_in[22];

    char* wsb = (char*)d_ws;
    float*          R      = (float*)(wsb + 0);                  // 2.25 MiB
    float*          scal   = (float*)(wsb + 2359296);            // 1 MiB
    float*          parts  = (float*)(wsb + 3407872);            // 8 MiB (2 slots)
    unsigned short* W      = (unsigned short*)(wsb + 11796480);  // 1.375 MiB
    unsigned short* Vthi   = (unsigned short*)(wsb + 13238272);  // 2 MiB
    unsigned short* Vtlo   = (unsigned short*)(wsb + 15335424);  // 2 MiB
    unsigned short* Qf     = (unsigned short*)(wsb + 17432576);  // 256 KiB
    unsigned short* Kf     = (unsigned short*)(wsb + 17694720);  // 256 KiB
    float*          gtab   = (float*)(wsb + 17956864);           // 4 KiB
    float*          jkT    = (float*)(wsb + 17977344);           // 64 KiB
    float*          kmT    = (float*)(wsb + 18042880);           // 64 KiB
    unsigned short* Ahi    = (unsigned short*)(wsb + 18108416);  // 4 MiB
    unsigned short* Alo    = (unsigned short*)(wsb + 22302720);  // 4 MiB
    unsigned short* xb     = (unsigned short*)(wsb + 26497024);  // 2 MiB
    unsigned short* locb   = (unsigned short*)(wsb + 28594176);  // 2 MiB

    float* out = (float*)d_out;

    k_prep_w<<<305, 256, 0, stream>>>(keyw, qryw, g1w, vw, outw, x, pf, W, xb, gtab);
    k_gemm1v<<<448, 256, 0, stream>>>(xb, W, g1b, vb, R, Vthi, Vtlo);
    k_phasor<<<NROW / 4, 256, 0, stream>>>(R, g2w, g2b, scal, jkT);
    k_scan16<<<16, 256, 0, stream>>>(jkT, kmT);
    k_build<<<256, 256, 0, stream>>>(scal, kmT, rscale, rthr, sscale, sbias, setw, Qf, Kf);
    k_buildA<<<2 * 136, 256, 0, stream>>>(Qf, Kf, scal, gtab, posw, Ahi, Alo);
    k_avH<<<512, 256, 0, stream>>>(Ahi, Alo, Vthi, Vtlo, parts);
    k_ln2<<<NROW, 512, 0, stream>>>(parts, lng, lnb, locb);
    k_gemm_out<<<256, 256, 0, stream>>>(locb, W + (size_t)896 * 512, outb, x, out);
}

// Round 11
// 165.024 us; speedup vs baseline: 1.0231x; 1.0231x over previous
//
#include <hip/hip_runtime.h>
#include <math.h>

#define B_ 2
#define L_ 1024
#define D_ 512
#define NROW 2048
#define RS 288                  // R stride: key16|query16|g1 256
#define PI_F 3.14159274f
#define TWO_PI_F 6.28318548f

typedef __attribute__((ext_vector_type(8))) short bf16x8;
typedef __attribute__((ext_vector_type(4))) float f32x4;

__device__ __forceinline__ unsigned short f2bf(float f) {
    unsigned u = __float_as_uint(f);
    unsigned r = (u + 0x7FFFu + ((u >> 16) & 1u)) >> 16;
    return (unsigned short)r;
}
__device__ __forceinline__ float bf2f(unsigned short h) {
    return __uint_as_float((unsigned)h << 16);
}
__device__ __forceinline__ unsigned pack2(float a, float b) {
    return (unsigned)f2bf(a) | ((unsigned)f2bf(b) << 16);
}

// ---------------- weight prep + x cast + gtab (verified R9) ----------------
__global__ __launch_bounds__(256) void k_prep_w(
    const float* __restrict__ keyw, const float* __restrict__ qryw,
    const float* __restrict__ g1w, const float* __restrict__ vw,
    const float* __restrict__ outw, const float* __restrict__ x,
    const float* __restrict__ pf,
    unsigned short* __restrict__ W, unsigned short* __restrict__ xb,
    float* __restrict__ gtab)
{
    const int bx = blockIdx.x;
    const int tid = threadIdx.x;
    if (bx >= 304) {                       // gtab
        #pragma unroll
        for (int j = 0; j < 4; ++j) {
            const int l = tid * 4 + j;
            float g = 0.f;
            #pragma unroll
            for (int p = 0; p < 16; ++p)
                g += cosf(TWO_PI_F * (float)l * pf[p]);
            gtab[l] = g;
        }
        return;
    }
    if (bx >= 176) {                       // x cast
        const int chunk = (bx - 176) * 2048;
        const float4* x4 = (const float4*)x;
        ushort4* xb4 = (ushort4*)xb;
        #pragma unroll
        for (int j = 0; j < 8; ++j) {
            float4 v = x4[chunk + j * 256 + tid];
            ushort4 o;
            o.x = f2bf(v.x); o.y = f2bf(v.y); o.z = f2bf(v.z); o.w = f2bf(v.w);
            xb4[chunk + j * 256 + tid] = o;
        }
        return;
    }
    const int nt = bx % 22;
    const int kt = bx / 22;
    const int n0 = nt * 64, k0 = kt * 64;
    __shared__ unsigned short tile[64 * 68];
    const int tn = tid & 63;
    const int tk4 = tid >> 6;
    const int n = n0 + tn;
    const float* src = nullptr; int stride = 0, col = 0;
    if (n < 16)        { src = keyw; stride = 16;  col = n; }
    else if (n < 32)   { src = qryw; stride = 16;  col = n - 16; }
    else if (n < 288)  { src = g1w;  stride = 256; col = n - 32; }
    else if (n < 800)  { src = vw;   stride = 512; col = n - 288; }
    else if (n < 896)  { src = nullptr; }
    else               { src = outw; stride = 512; col = n - 896; }
    #pragma unroll
    for (int r = 0; r < 16; ++r) {
        int k = k0 + tk4 * 16 + r;
        float v = src ? src[(size_t)k * stride + col] : 0.f;
        tile[(tk4 * 16 + r) * 68 + tn] = f2bf(v);
    }
    __syncthreads();
    #pragma unroll
    for (int r = 0; r < 16; ++r) {
        int nn = n0 + tk4 * 16 + r;
        W[(size_t)nn * 512 + k0 + tn] = tile[tn * 68 + tk4 * 16 + r];
    }
}

// ---------------- GEMM1 (64x64 tiles, 448 blocks): A=xb bf16; R + Vt hi/lo (verified R9) ----------------
__global__ __launch_bounds__(256) void k_gemm1v(
    const unsigned short* __restrict__ xb,
    const unsigned short* __restrict__ Bt,
    const float* __restrict__ g1b, const float* __restrict__ vb,
    float* __restrict__ R,
    unsigned short* __restrict__ Vthi, unsigned short* __restrict__ Vtlo)
{
    __shared__ unsigned short As[64 * 32];
    __shared__ unsigned short Bs[64 * 32];
    const int tid = threadIdx.x;
    const int w = tid >> 6;
    const int lane = tid & 63;
    const int m0 = blockIdx.y * 64;
    const int n0 = blockIdx.x * 64;
    const int srow = tid >> 2;
    const int scol = (tid & 3) * 8;
    const int quad = lane >> 4, r16 = lane & 15;

    f32x4 acc[4];
    #pragma unroll
    for (int mt = 0; mt < 4; ++mt) acc[mt] = (f32x4){0.f, 0.f, 0.f, 0.f};

    const unsigned short* ap = xb + (size_t)(m0 + srow) * 512 + scol;
    const unsigned short* bp = Bt + (size_t)(n0 + srow) * 512 + scol;

    for (int k0 = 0; k0 < 512; k0 += 32) {
        int4 av = *(const int4*)(ap + k0);
        int4 bv = *(const int4*)(bp + k0);
        __syncthreads();
        *(int4*)&As[srow * 32 + scol] = av;
        *(int4*)&Bs[srow * 32 + scol] = bv;
        __syncthreads();
        bf16x8 bfr = *(const bf16x8*)&Bs[(w * 16 + r16) * 32 + quad * 8];
        #pragma unroll
        for (int mt = 0; mt < 4; ++mt) {
            bf16x8 af = *(const bf16x8*)&As[(mt * 16 + r16) * 32 + quad * 8];
            acc[mt] = __builtin_amdgcn_mfma_f32_16x16x32_bf16(af, bfr, acc[mt], 0, 0, 0);
        }
    }

    const int n = n0 + w * 16 + r16;
    if (n < 288) {
        const float bias = (n >= 32) ? g1b[n - 32] : 0.f;
        #pragma unroll
        for (int mt = 0; mt < 4; ++mt)
            #pragma unroll
            for (int i = 0; i < 4; ++i) {
                const int m = m0 + mt * 16 + quad * 4 + i;
                R[(size_t)m * RS + n] = acc[mt][i] + bias;
            }
    } else if (n < 800) {
        const int d = n - 288;
        const float bias = vb[d];
        #pragma unroll
        for (int mt = 0; mt < 4; ++mt) {
            ushort4 h4, l4;
            #pragma unroll
            for (int i = 0; i < 4; ++i) {
                float v = acc[mt][i] + bias;
                unsigned short hi = f2bf(v);
                ((unsigned short*)&h4)[i] = hi;
                ((unsigned short*)&l4)[i] = f2bf(v - bf2f(hi));
            }
            const size_t vo = (size_t)d * 2048 + m0 + mt * 16 + quad * 4;
            *(ushort4*)&Vthi[vo] = h4;
            *(ushort4*)&Vtlo[vo] = l4;
        }
    }
}

// ---------------- phasors, jk/jq, gate + compact jkT (verified R7/R9) ----------------
__global__ __launch_bounds__(256) void k_phasor(
    const float* __restrict__ R,
    const float* __restrict__ g2w, const float* __restrict__ g2b,
    float* __restrict__ scal, float* __restrict__ jkT)
{
    const int row = blockIdx.x * 4 + (threadIdx.x >> 6);
    const int lane = threadIdx.x & 63;
    const int b = row >> 10, l = row & (L_ - 1);
    float* sc = scal + (size_t)row * 128;
    const float* r = R + (size_t)row * RS;

    float part = 0.f;
    #pragma unroll
    for (int j = 0; j < 4; ++j) {
        float v = r[32 + lane * 4 + j];
        float h = 0.5f * v * (1.0f + erff(v * 0.70710678f));
        part += h * g2w[lane * 4 + j];
    }
    #pragma unroll
    for (int off = 32; off > 0; off >>= 1) part += __shfl_down(part, off, 64);
    if (lane == 0) sc[112] = 1.0f / (1.0f + expf(-(part + g2b[0])));

    float pr = 1.f, pim = 0.f;
    if (lane < 32) {
        float a = tanhf(r[lane]) * PI_F;
        float sv, cv;
        sincosf(a, &sv, &cv);
        int t = lane & 15;
        if (lane < 16) { sc[t] = cv; sc[16 + t] = sv; }
        else           { sc[32 + t] = cv; sc[48 + t] = sv; }
        pr = cv; pim = sv;
    }
    #pragma unroll
    for (int m = 4; m <= 8; m <<= 1) {
        float orr = __shfl_xor(pr, m, 64);
        float oii = __shfl_xor(pim, m, 64);
        float nr = pr * orr - pim * oii;
        float ni = pr * oii + pim * orr;
        pr = nr; pim = ni;
    }
    if (lane < 4) {
        sc[64 + lane] = pr; sc[68 + lane] = pim;
        jkT[(size_t)(b * 8 + lane) * L_ + l]     = pr;
        jkT[(size_t)(b * 8 + 4 + lane) * L_ + l] = pim;
    } else if (lane >= 16 && lane < 20) {
        sc[72 + lane - 16] = pr; sc[76 + lane - 16] = pim;
    }
}

// ---------------- wide block scan: 16 channels (verified R8/R9) ----------------
__global__ __launch_bounds__(256) void k_scan16(
    const float* __restrict__ jkT, float* __restrict__ kmT)
{
    const int bx = blockIdx.x;
    const int tid = threadIdx.x;
    const int lane = tid & 63, wv = tid >> 6;
    __shared__ float wtot[4];
    float4 v = ((const float4*)(jkT + (size_t)bx * L_))[tid];
    float s = v.x + v.y + v.z + v.w;
    float incl = s;
    #pragma unroll
    for (int off = 1; off < 64; off <<= 1) {
        float o = __shfl_up(incl, off, 64);
        if (lane >= off) incl += o;
    }
    if (lane == 63) wtot[wv] = incl;
    __syncthreads();
    float pre = incl - s;
    for (int w2 = 0; w2 < wv; ++w2) pre += wtot[w2];
    float4 out;
    out.x = pre;
    out.y = pre + v.x;
    out.z = out.y + v.y;
    out.w = out.z + v.z;
    ((float4*)(kmT + (size_t)bx * L_))[tid] = out;
}

// ---------------- build: wgv inline + Qf/Kf rows (verified R8/R9) ----------------
__global__ __launch_bounds__(256) void k_build(
    const float* __restrict__ scal, const float* __restrict__ kmT,
    const float* __restrict__ res_scale, const float* __restrict__ res_thr,
    const float* __restrict__ sur_scale, const float* __restrict__ sur_bias,
    const float* __restrict__ setw,
    unsigned short* __restrict__ Qf, unsigned short* __restrict__ Kf)
{
    const int rowi = blockIdx.x * 8 + (threadIdx.x >> 5);
    const int sub = threadIdx.x & 31;
    const int b = rowi >> 10, l = rowi & (L_ - 1);
    const float* sc = scal + (size_t)rowi * 128;

    float mag = 0.f;
    #pragma unroll
    for (int pp = 0; pp < 4; ++pp) {
        float kmr = kmT[(size_t)(b * 8 + pp) * L_ + l];
        float kmi = kmT[(size_t)(b * 8 + 4 + pp) * L_ + l];
        float jqr = sc[72 + pp], jqi = sc[76 + pp];
        float re = kmr * jqr + kmi * jqi;
        float im = kmi * jqr - kmr * jqi;
        mag += sqrtf(re * re + im * im);
    }
    mag *= 0.25f;
    float posn = fmaxf((float)l, 1.0f);
    float nres = mag / sqrtf(posn);
    float scl = fminf(fmaxf(res_scale[0], 1.0f), 20.0f);
    float thr = fminf(fmaxf(res_thr[0], 0.1f), 0.9f);
    float sur = 0.5f * (1.0f - tanhf(scl * (nres - thr)));
    float wgv = 1.0f / (1.0f + expf(-(sur_scale[0] * (sur - 0.5f) + sur_bias[0])));

    const float gate = sc[112];
    float s0 = setw[0], s1 = setw[1], s2 = setw[2], s3 = setw[3];
    float mx = fmaxf(fmaxf(s0, s1), fmaxf(s2, s3));
    float e0 = expf(s0 - mx), e1 = expf(s1 - mx), e2 = expf(s2 - mx), e3 = expf(s3 - mx);
    float esum = e0 + e1 + e2 + e3;
    const float qs = 0.2f * gate;

    unsigned* qp = (unsigned*)(Qf + (size_t)rowi * 64);
    unsigned* kp = (unsigned*)(Kf + (size_t)rowi * 64);
    if (sub < 16) {
        float wgrp = ((sub >> 2) == 0 ? e0 : (sub >> 2) == 1 ? e1 : (sub >> 2) == 2 ? e2 : e3) / esum;
        qp[sub] = pack2(qs * wgrp * sc[32 + sub], qs * wgrp * sc[48 + sub]);
        kp[sub] = pack2(wgv * sc[sub], wgv * sc[16 + sub]);
    } else if (sub < 20) {
        int p = sub - 16;
        qp[16 + p] = pack2(qs * sc[72 + p], qs * sc[76 + p]);
        kp[16 + p] = pack2(wgv * sc[64 + p], wgv * sc[68 + p]);
    } else {
        qp[sub] = 0u; kp[sub] = 0u;
    }
}

// ---------------- build A (tril 64x64 tiles) (verified R3/R8/R9) ----------------
__global__ __launch_bounds__(256) void k_buildA(
    const unsigned short* __restrict__ Qf, const unsigned short* __restrict__ Kf,
    const float* __restrict__ scal, const float* __restrict__ gtab,
    const float* __restrict__ posw,
    unsigned short* __restrict__ Ahi, unsigned short* __restrict__ Alo)
{
    const int bx = blockIdx.x;
    const int b = bx / 136;
    const int r = bx % 136;
    int ti = 0;
    while ((ti + 1) * (ti + 2) / 2 <= r) ++ti;
    const int tj = r - ti * (ti + 1) / 2;

    __shared__ unsigned short Qs[64 * 72];
    __shared__ unsigned short Ks[64 * 72];
    const int tid = threadIdx.x;
    const int srow = tid >> 2;
    const int sc16 = (tid & 3) * 16;
    {
        const unsigned short* qsrc = Qf + ((size_t)(b * L_ + ti * 64 + srow)) * 64 + sc16;
        const unsigned short* ksrc = Kf + ((size_t)(b * L_ + tj * 64 + srow)) * 64 + sc16;
        *(int4*)&Qs[srow * 72 + sc16]     = *(const int4*)(qsrc);
        *(int4*)&Qs[srow * 72 + sc16 + 8] = *(const int4*)(qsrc + 8);
        *(int4*)&Ks[srow * 72 + sc16]     = *(const int4*)(ksrc);
        *(int4*)&Ks[srow * 72 + sc16 + 8] = *(const int4*)(ksrc + 8);
    }
    __syncthreads();

    const int w = tid >> 6;
    const int lane = tid & 63;
    const int quad = lane >> 4, r16 = lane & 15;
    f32x4 acc[4];
    #pragma unroll
    for (int mt = 0; mt < 4; ++mt) acc[mt] = (f32x4){0.f, 0.f, 0.f, 0.f};
    #pragma unroll
    for (int kk = 0; kk < 2; ++kk) {
        bf16x8 bfr = *(const bf16x8*)&Ks[(w * 16 + r16) * 72 + kk * 32 + quad * 8];
        #pragma unroll
        for (int mt = 0; mt < 4; ++mt) {
            bf16x8 af = *(const bf16x8*)&Qs[(mt * 16 + r16) * 72 + kk * 32 + quad * 8];
            acc[mt] = __builtin_amdgcn_mfma_f32_16x16x32_bf16(af, bfr, acc[mt], 0, 0, 0);
        }
    }
    const float sw = 1.0f / (1.0f + expf(-posw[0]));
    const int lp = tj * 64 + w * 16 + r16;
    #pragma unroll
    for (int mt = 0; mt < 4; ++mt) {
        #pragma unroll
        for (int i = 0; i < 4; ++i) {
            const int l = ti * 64 + mt * 16 + quad * 4 + i;
            const int dl = l - lp;
            float v = 0.f;
            if (dl >= 0) {
                float gate = scal[((size_t)(b * L_ + l)) * 128 + 112];
                v = acc[mt][i] + (1.0f - gate) * sw * gtab[dl];
            }
            unsigned short hi = f2bf(v);
            unsigned short lo = f2bf(v - bf2f(hi));
            const size_t off = ((size_t)(b * L_ + l)) * 1024 + lp;
            Ahi[off] = hi;
            Alo[off] = lo;
        }
    }
}

// ---------------- AV GEMM, h-split + b-flip balance (verified R8/R9) ----------------
__global__ __launch_bounds__(256) void k_avH(
    const unsigned short* __restrict__ Ahi, const unsigned short* __restrict__ Alo,
    const unsigned short* __restrict__ Vthi, const unsigned short* __restrict__ Vtlo,
    float* __restrict__ parts)
{
    const int bx = blockIdx.x;          // b(1)|ti0(4)|nj(3)|h(1) = 512
    const int h  = bx & 1;
    const int nj = (bx >> 1) & 7;
    const int ti0 = (bx >> 4) & 15;
    const int b  = bx >> 8;
    const int ti = b ? (15 - ti0) : ti0;
    const int m0 = ti * 64, n0 = nj * 64;
    const int nh = (ti + 2) >> 1;
    const int kbeg = (h ? nh : 0) * 64;
    const int kend = (h ? (ti + 1) : nh) * 64;
    float* prt = parts + (size_t)h * NROW * 512;

    __shared__ unsigned short Ash[64 * 32];
    __shared__ unsigned short Asl[64 * 32];
    __shared__ unsigned short Bsh[64 * 32];
    __shared__ unsigned short Bsl[64 * 32];
    const int tid = threadIdx.x;
    const int w = tid >> 6;
    const int lane = tid & 63;
    const int srow = tid >> 2;
    const int scol = (tid & 3) * 8;
    const int quad = lane >> 4, r16 = lane & 15;

    f32x4 acc[4];
    #pragma unroll
    for (int mt = 0; mt < 4; ++mt) acc[mt] = (f32x4){0.f, 0.f, 0.f, 0.f};

    const unsigned short* aph = Ahi + ((size_t)(b * L_ + m0 + srow)) * 1024 + scol;
    const unsigned short* apl = Alo + ((size_t)(b * L_ + m0 + srow)) * 1024 + scol;
    const unsigned short* bph = Vthi + (size_t)(n0 + srow) * 2048 + b * L_ + scol;
    const unsigned short* bpl = Vtlo + (size_t)(n0 + srow) * 2048 + b * L_ + scol;

    for (int k0 = kbeg; k0 < kend; k0 += 32) {
        int4 ah = *(const int4*)(aph + k0);
        int4 al = *(const int4*)(apl + k0);
        int4 bh = *(const int4*)(bph + k0);
        int4 bl = *(const int4*)(bpl + k0);
        __syncthreads();
        *(int4*)&Ash[srow * 32 + scol] = ah;
        *(int4*)&Asl[srow * 32 + scol] = al;
        *(int4*)&Bsh[srow * 32 + scol] = bh;
        *(int4*)&Bsl[srow * 32 + scol] = bl;
        __syncthreads();
        bf16x8 bh8 = *(const bf16x8*)&Bsh[(w * 16 + r16) * 32 + quad * 8];
        bf16x8 bl8 = *(const bf16x8*)&Bsl[(w * 16 + r16) * 32 + quad * 8];
        #pragma unroll
        for (int mt = 0; mt < 4; ++mt) {
            bf16x8 ah8 = *(const bf16x8*)&Ash[(mt * 16 + r16) * 32 + quad * 8];
            bf16x8 al8 = *(const bf16x8*)&Asl[(mt * 16 + r16) * 32 + quad * 8];
            acc[mt] = __builtin_amdgcn_mfma_f32_16x16x32_bf16(ah8, bh8, acc[mt], 0, 0, 0);
            acc[mt] = __builtin_amdgcn_mfma_f32_16x16x32_bf16(ah8, bl8, acc[mt], 0, 0, 0);
            acc[mt] = __builtin_amdgcn_mfma_f32_16x16x32_bf16(al8, bh8, acc[mt], 0, 0, 0);
        }
    }
    const int n = n0 + w * 16 + r16;
    #pragma unroll
    for (int mt = 0; mt < 4; ++mt)
        #pragma unroll
        for (int i = 0; i < 4; ++i)
            prt[((size_t)(b * L_ + m0 + mt * 16 + quad * 4 + i)) * 512 + n] = acc[mt][i];
}

// ---------------- LN: y = (p0+p1)/nf, LayerNorm, bf16 out (verified R9) ----------------
__global__ __launch_bounds__(512) void k_ln2(
    const float* __restrict__ parts,
    const float* __restrict__ lng, const float* __restrict__ lnb,
    unsigned short* __restrict__ locb)
{
    const int row = blockIdx.x;
    const int l = row & (L_ - 1);
    const int d = threadIdx.x;
    __shared__ float red[16];
    float y = (parts[(size_t)row * 512 + d]
             + parts[(size_t)NROW * 512 + (size_t)row * 512 + d])
            / sqrtf(4.0f * (float)(l + 1));
    float s = y, s2v = y * y;
    #pragma unroll
    for (int off = 32; off > 0; off >>= 1) {
        s   += __shfl_down(s, off, 64);
        s2v += __shfl_down(s2v, off, 64);
    }
    const int lane = d & 63, wv = d >> 6;
    if (lane == 0) { red[wv] = s; red[8 + wv] = s2v; }
    __syncthreads();
    float su = 0.f, sq = 0.f;
    #pragma unroll
    for (int w2 = 0; w2 < 8; ++w2) { su += red[w2]; sq += red[8 + w2]; }
    float mu = su * (1.0f / 512.0f);
    float var = sq * (1.0f / 512.0f) - mu * mu;
    float rstd = rsqrtf(var + 1e-5f);
    float yn = (y - mu) * rstd * lng[d] + lnb[d];
    locb[(size_t)row * 512 + d] = f2bf(yn);
}

// ---------------- out GEMM (verified R1/R3/R9): out = x + locb @ OWt^T + out_b ----------------
__global__ __launch_bounds__(256) void k_gemm_out(
    const unsigned short* __restrict__ A,
    const unsigned short* __restrict__ Bt,
    const float* __restrict__ bias, const float* __restrict__ resid,
    float* __restrict__ out)
{
    __shared__ unsigned short As[64 * 32];
    __shared__ unsigned short Bs[64 * 32];
    const int tid = threadIdx.x;
    const int w = tid >> 6;
    const int lane = tid & 63;
    const int m0 = blockIdx.y * 64;
    const int n0 = blockIdx.x * 64;
    const int srow = tid >> 2;
    const int scol = (tid & 3) * 8;
    const int quad = lane >> 4, r16 = lane & 15;

    f32x4 acc[4];
    #pragma unroll
    for (int mt = 0; mt < 4; ++mt) acc[mt] = (f32x4){0.f, 0.f, 0.f, 0.f};

    const unsigned short* ap = A  + (size_t)(m0 + srow) * 512 + scol;
    const unsigned short* bp = Bt + (size_t)(n0 + srow) * 512 + scol;

    for (int k0 = 0; k0 < 512; k0 += 32) {
        int4 av = *(const int4*)(ap + k0);
        int4 bv = *(const int4*)(bp + k0);
        __syncthreads();
        *(int4*)&As[srow * 32 + scol] = av;
        *(int4*)&Bs[srow * 32 + scol] = bv;
        __syncthreads();
        bf16x8 bfr = *(const bf16x8*)&Bs[(w * 16 + r16) * 32 + quad * 8];
        #pragma unroll
        for (int mt = 0; mt < 4; ++mt) {
            bf16x8 af = *(const bf16x8*)&As[(mt * 16 + r16) * 32 + quad * 8];
            acc[mt] = __builtin_amdgcn_mfma_f32_16x16x32_bf16(af, bfr, acc[mt], 0, 0, 0);
        }
    }
    const int n = n0 + w * 16 + r16;
    const float bn = bias[n];
    #pragma unroll
    for (int mt = 0; mt < 4; ++mt) {
        #pragma unroll
        for (int i = 0; i < 4; ++i) {
            const int m = m0 + mt * 16 + quad * 4 + i;
            out[(size_t)m * 512 + n] = acc[mt][i] + bn + resid[(size_t)m * 512 + n];
        }
    }
}

extern "C" void kernel_launch(void* const* d_in, const int* in_sizes, int n_in,
                              void* d_out, int out_size, void* d_ws, size_t ws_size,
                              hipStream_t stream)
{
    const float* x      = (const float*)d_in[0];
    const float* keyw   = (const float*)d_in[1];
    const float* qryw   = (const float*)d_in[2];
    const float* vw     = (const float*)d_in[4];
    const float* vb     = (const float*)d_in[5];
    const float* lng    = (const float*)d_in[6];
    const float* lnb    = (const float*)d_in[7];
    const float* outw   = (const float*)d_in[8];
    const float* outb   = (const float*)d_in[9];
    const float* setw   = (const float*)d_in[10];
    const float* pf     = (const float*)d_in[11];
    const float* posw   = (const float*)d_in[12];
    const float* g1w    = (const float*)d_in[13];
    const float* g1b    = (const float*)d_in[14];
    const float* g2w    = (const float*)d_in[15];
    const float* g2b    = (const float*)d_in[16];
    const float* sscale = (const float*)d_in[19];
    const float* sbias  = (const float*)d_in[20];
    const float* rscale = (const float*)d_in[21];
    const float* rthr   = (const float*)d_in[22];

    char* wsb = (char*)d_ws;
    float*          R      = (float*)(wsb + 0);                  // 2.25 MiB
    float*          scal   = (float*)(wsb + 2359296);            // 1 MiB
    float*          parts  = (float*)(wsb + 3407872);            // 8 MiB (2 slots)
    unsigned short* W      = (unsigned short*)(wsb + 11796480);  // 1.375 MiB
    unsigned short* Vthi   = (unsigned short*)(wsb + 13238272);  // 2 MiB
    unsigned short* Vtlo   = (unsigned short*)(wsb + 15335424);  // 2 MiB
    unsigned short* Qf     = (unsigned short*)(wsb + 17432576);  // 256 KiB
    unsigned short* Kf     = (unsigned short*)(wsb + 17694720);  // 256 KiB
    float*          gtab   = (float*)(wsb + 17956864);           // 4 KiB
    float*          jkT    = (float*)(wsb + 17977344);           // 64 KiB
    float*          kmT    = (float*)(wsb + 18042880);           // 64 KiB
    unsigned short* Ahi    = (unsigned short*)(wsb + 18108416);  // 4 MiB
    unsigned short* Alo    = (unsigned short*)(wsb + 22302720);  // 4 MiB
    unsigned short* xb     = (unsigned short*)(wsb + 26497024);  // 2 MiB
    unsigned short* locb   = (unsigned short*)(wsb + 28594176);  // 2 MiB

    float* out = (float*)d_out;

    k_prep_w<<<305, 256, 0, stream>>>(keyw, qryw, g1w, vw, outw, x, pf, W, xb, gtab);
    k_gemm1v<<<dim3(14, 32), 256, 0, stream>>>(xb, W, g1b, vb, R, Vthi, Vtlo);
    k_phasor<<<NROW / 4, 256, 0, stream>>>(R, g2w, g2b, scal, jkT);
    k_scan16<<<16, 256, 0, stream>>>(jkT, kmT);
    k_build<<<256, 256, 0, stream>>>(scal, kmT, rscale, rthr, sscale, sbias, setw, Qf, Kf);
    k_buildA<<<2 * 136, 256, 0, stream>>>(Qf, Kf, scal, gtab, posw, Ahi, Alo);
    k_avH<<<512, 256, 0, stream>>>(Ahi, Alo, Vthi, Vtlo, parts);
    k_ln2<<<NROW, 512, 0, stream>>>(parts, lng, lnb, locb);
    k_gemm_out<<<dim3(8, 32), 256, 0, stream>>>(locb, W + (size_t)896 * 512, outb, x, out);
}